// Round 8
// baseline (748.682 us; speedup 1.0000x reference)
//
#include <hip/hip_runtime.h>

#define SS  128
#define DD  512
#define NHH 8
#define DHH 64

typedef float  f4 __attribute__((ext_vector_type(4)));
typedef float  f2 __attribute__((ext_vector_type(2)));
typedef double d2 __attribute__((ext_vector_type(2)));

typedef const void __attribute__((address_space(1)))* gas_t;
typedef void __attribute__((address_space(3)))* las_t;

// ---- async stage: one 8-row (16 KB) chunk of X into LDS, linear layout -------
__device__ __forceinline__ void stage_chunk(const float* __restrict__ Xb,
                                            int c, int buf, int tid, float* XsF)
{
    const int wid  = tid >> 6;
    const int lane = tid & 63;
    const float* gsrc = Xb + (size_t)c * (8 * DD);
    #pragma unroll
    for (int p = 0; p < 4; ++p) {
        const int gbase = p * 256 + wid * 64;             // 16B-granule index base
        const float* gp = gsrc + (size_t)(gbase + lane) * 4;
        float* lp = XsF + (size_t)buf * 4096 + (size_t)gbase * 4; // wave-uniform
        __builtin_amdgcn_global_load_lds((gas_t)gp, (las_t)lp, 16, 0, 0);
    }
}

// ============ FUSED: qproj (f64) + flash attention core + zout (f32) ==========
// One block per batch element b. Phases:
//  Q: q[b] = Wq.x_non[b] + bq   (f64, wave-per-output reduce, coalesced Wq)
//  (verified round-1 core: qbk, t = Wk_h^T q_h, flash loop over X chunks)
//  Z: z[b,o] = u'[h].Wv[o] + bv[o], o = h*64+j   (f32, wave-per-output reduce)
__global__ __launch_bounds__(256, 4) void fused_kernel(
    const float* __restrict__ x_non, const float* __restrict__ x_seq,
    const int* __restrict__ mask,
    const float* __restrict__ Wq, const float* __restrict__ bq,
    const float* __restrict__ Wk, const float* __restrict__ bk,
    const float* __restrict__ Wv, const float* __restrict__ bv,
    float* __restrict__ out)
{
    const int tid = threadIdx.x;
    const int b   = blockIdx.x;
    const float* Xb = x_seq + (size_t)b * (SS * DD);

    const int hp    = tid >> 6;        // wave id; heads 2hp, 2hp+1 in flash
    const int rhalf = (tid >> 5) & 1;  // chunk row half
    const int k16   = tid & 31;        // 16-col group: cols {k16*2 + 64p}
    const int wid   = tid >> 6;
    const int lane  = tid & 63;

    __shared__ __attribute__((aligned(16))) union {
        double T[8][512];              // 32 KB: t, head-major (pre-flash)
        float  Xs[2][8][512];          // 32 KB: double-buffered X chunks (flash)
        float  U[8][512];              // 16 KB: normalized u' (Z phase)
    } sh;
    __shared__ __attribute__((aligned(16))) union {
        double qd[512];                // 4 KB: q[b] (pre-flash)
        int    mk[1024];               // 4 KB: mask[b] (flash)
    } sh2;
    __shared__ double qbks[8];
    __shared__ __attribute__((aligned(16))) float xns[512];

    float* XsF = &sh.Xs[0][0][0];

    // ---- Phase Q: q[b] (f64), replaces qproj kernel + qws roundtrip ----
    xns[tid]       = x_non[(size_t)b * DD + tid];
    xns[tid + 256] = x_non[(size_t)b * DD + tid + 256];
    __syncthreads();

    {
        // lane's x fragment (k = lane*8 .. +7), hoisted to f64 regs once
        double xd[8];
        {
            f4 xa = *(const f4*)&xns[lane * 8];
            f4 xb = *(const f4*)&xns[lane * 8 + 4];
            xd[0] = (double)xa[0]; xd[1] = (double)xa[1];
            xd[2] = (double)xa[2]; xd[3] = (double)xa[3];
            xd[4] = (double)xb[0]; xd[5] = (double)xb[1];
            xd[6] = (double)xb[2]; xd[7] = (double)xb[3];
        }
        // wave w computes outputs o = w*128 .. +127; coalesced Wq row reads
        #pragma unroll 2
        for (int i = 0; i < 128; ++i) {
            const int o = wid * 128 + i;
            const float* wp = Wq + (size_t)o * DD + lane * 8;
            f4 wa = *(const f4*)wp;
            f4 wb = *(const f4*)(wp + 4);
            double a = 0.0;
            a = fma((double)wa[0], xd[0], a);
            a = fma((double)wa[1], xd[1], a);
            a = fma((double)wa[2], xd[2], a);
            a = fma((double)wa[3], xd[3], a);
            a = fma((double)wb[0], xd[4], a);
            a = fma((double)wb[1], xd[5], a);
            a = fma((double)wb[2], xd[6], a);
            a = fma((double)wb[3], xd[7], a);
            #pragma unroll
            for (int off = 1; off < 64; off <<= 1) a += __shfl_xor(a, off);
            if (lane == 0) sh2.qd[o] = a + (double)bq[o];
        }
    }
    __syncthreads();

    // ---- qbk[h] = q_h . bk_h (wave 0, 8 lanes per head) ----
    if (tid < 64) {
        const int h = tid >> 3, part = tid & 7;
        double s = 0.0;
        #pragma unroll
        for (int ii = 0; ii < 8; ++ii) {
            int d = part * 8 + ii;
            s = fma(sh2.qd[h * DHH + d], (double)bk[h * DHH + d], s);
        }
        s += __shfl_xor(s, 1);
        s += __shfl_xor(s, 2);
        s += __shfl_xor(s, 4);
        if (part == 0) qbks[h] = s;
    }

    // ---- t: lanes = k (coalesced f4 Wk loads); d split across thread halves ----
    {
        const int kg = tid & 127, dh = tid >> 7;
        const int k4 = kg * 4;
        for (int hg = 0; hg < 2; ++hg) {
            double tacc[4][4];
            #pragma unroll
            for (int h4 = 0; h4 < 4; ++h4) {
                const int h = hg * 4 + h4;
                const float* wp = Wk + ((size_t)(h * DHH + dh * 32)) * DD + k4;
                double t0 = 0, t1 = 0, t2 = 0, t3 = 0;
                for (int d = 0; d < 32; ++d) {
                    f4 wv = *(const f4*)(wp + (size_t)d * DD);
                    double qv = sh2.qd[h * DHH + dh * 32 + d];
                    t0 = fma((double)wv[0], qv, t0);
                    t1 = fma((double)wv[1], qv, t1);
                    t2 = fma((double)wv[2], qv, t2);
                    t3 = fma((double)wv[3], qv, t3);
                }
                tacc[h4][0] = t0; tacc[h4][1] = t1; tacc[h4][2] = t2; tacc[h4][3] = t3;
            }
            if (dh == 1) {
                #pragma unroll
                for (int h4 = 0; h4 < 4; ++h4)
                    #pragma unroll
                    for (int e = 0; e < 4; ++e)
                        sh.T[hg * 4 + h4][k4 + e] = tacc[h4][e];
            }
            __syncthreads();
            if (dh == 0) {
                #pragma unroll
                for (int h4 = 0; h4 < 4; ++h4)
                    #pragma unroll
                    for (int e = 0; e < 4; ++e)
                        sh.T[hg * 4 + h4][k4 + e] += tacc[h4][e];
            }
            __syncthreads();
        }
    }

    // ---- t fragments to registers ----
    d2 treg[2][8];
    #pragma unroll
    for (int hh = 0; hh < 2; ++hh)
        #pragma unroll
        for (int p = 0; p < 8; ++p)
            treg[hh][p] = *(const d2*)&sh.T[hp * 2 + hh][k16 * 2 + 64 * p];
    float qbkf[2] = { (float)qbks[hp * 2], (float)qbks[hp * 2 + 1] };
    __syncthreads();                       // T fully read; Xs may be written

    // ---- stage mask[b] (reuses qd space) + first X chunk ----
    #pragma unroll
    for (int p = 0; p < 4; ++p)
        sh2.mk[tid + 256 * p] = mask[(size_t)b * (NHH * SS) + tid + 256 * p];
    stage_chunk(Xb, 0, 0, tid, XsF);
    asm volatile("s_waitcnt vmcnt(0)");
    __syncthreads();

    // ---- flash loop over 16 chunks of 8 rows (verified round-1 structure) ----
    float u[2][16];
    #pragma unroll
    for (int hh = 0; hh < 2; ++hh)
        #pragma unroll
        for (int j = 0; j < 16; ++j) u[hh][j] = 0.f;
    float m_run[2] = { -1e30f, -1e30f };
    float l_run[2] = { 0.f, 0.f };

    for (int c = 0; c < 16; ++c) {
        const int buf = c & 1;
        if (c < 15) stage_chunk(Xb, c + 1, buf ^ 1, tid, XsF);

        const float* Xc = XsF + buf * 4096 + (rhalf * 4) * DD + k16 * 2;

        double acc[2][4];
        #pragma unroll
        for (int hh = 0; hh < 2; ++hh)
            #pragma unroll
            for (int r = 0; r < 4; ++r) acc[hh][r] = 0.0;

        #pragma unroll
        for (int r = 0; r < 4; ++r) {
            #pragma unroll
            for (int p = 0; p < 8; ++p) {
                f2 xv = *(const f2*)&Xc[r * DD + p * 64];
                double x0 = (double)xv[0], x1 = (double)xv[1];
                #pragma unroll
                for (int hh = 0; hh < 2; ++hh) {
                    acc[hh][r] = fma(x0, treg[hh][p][0], acc[hh][r]);
                    acc[hh][r] = fma(x1, treg[hh][p][1], acc[hh][r]);
                }
            }
        }

        float Lown[2][4];
        #pragma unroll
        for (int hh = 0; hh < 2; ++hh)
            #pragma unroll
            for (int r = 0; r < 4; ++r) {
                float s = (float)acc[hh][r];
                s += __shfl_xor(s, 1);
                s += __shfl_xor(s, 2);
                s += __shfl_xor(s, 4);
                s += __shfl_xor(s, 8);
                s += __shfl_xor(s, 16);
                s = floorf((s + qbkf[hh]) * 0.125f);
                const int row = c * 8 + rhalf * 4 + r;
                if (sh2.mk[(hp * 2 + hh) * SS + row] == 0) s = -1e9f;
                Lown[hh][r] = s;
            }

        float pw[2][4];
        #pragma unroll
        for (int hh = 0; hh < 2; ++hh) {
            float Loth[4];
            #pragma unroll
            for (int r = 0; r < 4; ++r) Loth[r] = __shfl_xor(Lown[hh][r], 32);
            float cmax = fmaxf(
                fmaxf(fmaxf(Lown[hh][0], Lown[hh][1]), fmaxf(Lown[hh][2], Lown[hh][3])),
                fmaxf(fmaxf(Loth[0], Loth[1]), fmaxf(Loth[2], Loth[3])));
            float mnew = fmaxf(m_run[hh], cmax);
            if (mnew != m_run[hh]) {
                float fs = __expf(m_run[hh] - mnew);
                #pragma unroll
                for (int j = 0; j < 16; ++j) u[hh][j] *= fs;
                l_run[hh] *= fs;
                m_run[hh] = mnew;
            }
            float ps = 0.f;
            #pragma unroll
            for (int r = 0; r < 4; ++r) { pw[hh][r] = __expf(Lown[hh][r] - mnew); ps += pw[hh][r]; }
            #pragma unroll
            for (int r = 0; r < 4; ++r) ps += __expf(Loth[r] - mnew);
            l_run[hh] += ps;
        }

        #pragma unroll
        for (int r = 0; r < 4; ++r) {
            #pragma unroll
            for (int p = 0; p < 8; ++p) {
                f2 xv = *(const f2*)&Xc[r * DD + p * 64];
                #pragma unroll
                for (int hh = 0; hh < 2; ++hh) {
                    u[hh][p * 2]     = fmaf(pw[hh][r], xv[0], u[hh][p * 2]);
                    u[hh][p * 2 + 1] = fmaf(pw[hh][r], xv[1], u[hh][p * 2 + 1]);
                }
            }
        }

        asm volatile("s_waitcnt vmcnt(0)");
        __syncthreads();
    }

    // ---- merge row-halves; write normalized u' to LDS (replaces uws) ----
    #pragma unroll
    for (int hh = 0; hh < 2; ++hh)
        #pragma unroll
        for (int j = 0; j < 16; ++j) u[hh][j] += __shfl_xor(u[hh][j], 32);

    {
        const int h = hp * 2 + rhalf;       // lane owns one head after merge
        const float inv = 1.0f / (rhalf ? l_run[1] : l_run[0]);
        #pragma unroll
        for (int p = 0; p < 8; ++p) {
            f2 v;
            v[0] = (rhalf ? u[1][p * 2]     : u[0][p * 2])     * inv;
            v[1] = (rhalf ? u[1][p * 2 + 1] : u[0][p * 2 + 1]) * inv;
            *(f2*)&sh.U[h][k16 * 2 + p * 64] = v;
        }
    }
    __syncthreads();

    // ---- Phase Z: z[b, h*64+j] = u'[h] . Wv[o] + bv[o] (replaces zout) ----
    #pragma unroll
    for (int hh2 = 0; hh2 < 2; ++hh2) {
        const int h = wid * 2 + hh2;       // wave covers o = wid*128 .. +127
        f4 ua = *(const f4*)&sh.U[h][lane * 8];
        f4 ub = *(const f4*)&sh.U[h][lane * 8 + 4];
        #pragma unroll 2
        for (int j = 0; j < 64; ++j) {
            const int o = h * 64 + j;
            const float* wp = Wv + (size_t)o * DD + lane * 8;
            f4 wa = *(const f4*)wp;
            f4 wb = *(const f4*)(wp + 4);
            float a = 0.f;
            a = fmaf(wa[0], ua[0], a);
            a = fmaf(wa[1], ua[1], a);
            a = fmaf(wa[2], ua[2], a);
            a = fmaf(wa[3], ua[3], a);
            a = fmaf(wb[0], ub[0], a);
            a = fmaf(wb[1], ub[1], a);
            a = fmaf(wb[2], ub[2], a);
            a = fmaf(wb[3], ub[3], a);
            #pragma unroll
            for (int off = 1; off < 64; off <<= 1) a += __shfl_xor(a, off);
            if (lane == 0) out[(size_t)b * DD + o] = a + bv[o];
        }
    }
}

extern "C" void kernel_launch(void* const* d_in, const int* in_sizes, int n_in,
                              void* d_out, int out_size, void* d_ws, size_t ws_size,
                              hipStream_t stream) {
    const float* x_non = (const float*)d_in[0];
    const float* x_seq = (const float*)d_in[1];
    const int*   mask  = (const int*)d_in[2];
    const float* Wq    = (const float*)d_in[3];
    const float* bq    = (const float*)d_in[4];
    const float* Wk    = (const float*)d_in[5];
    const float* bk    = (const float*)d_in[6];
    const float* Wv    = (const float*)d_in[7];
    const float* bv    = (const float*)d_in[8];
    float*       out   = (float*)d_out;

    fused_kernel<<<1024, 256, 0, stream>>>(x_non, x_seq, mask,
                                           Wq, bq, Wk, bk, Wv, bv, out);
}

// Round 10
// 747.910 us; speedup vs baseline: 1.0010x; 1.0010x over previous
//
#include <hip/hip_runtime.h>

#define SS  128
#define DD  512
#define NHH 8
#define DHH 64

typedef float  f4 __attribute__((ext_vector_type(4)));
typedef float  f2 __attribute__((ext_vector_type(2)));
typedef double d2 __attribute__((ext_vector_type(2)));

typedef const void __attribute__((address_space(1)))* gas_t;
typedef void __attribute__((address_space(3)))* las_t;

// ---- async stage: one 8-row (16 KB) chunk of X into LDS, linear layout -------
__device__ __forceinline__ void stage_chunk(const float* __restrict__ Xb,
                                            int c, int buf, int tid, float* XsF)
{
    const int wid  = tid >> 6;
    const int lane = tid & 63;
    const float* gsrc = Xb + (size_t)c * (8 * DD);
    #pragma unroll
    for (int p = 0; p < 4; ++p) {
        const int gbase = p * 256 + wid * 64;             // 16B-granule index base
        const float* gp = gsrc + (size_t)(gbase + lane) * 4;
        float* lp = XsF + (size_t)buf * 4096 + (size_t)gbase * 4; // wave-uniform
        __builtin_amdgcn_global_load_lds((gas_t)gp, (las_t)lp, 16, 0, 0);
    }
}

// ============ FUSED: qproj (f64) + flash attention core + zout (f32) ==========
// One block per batch element b.
// NOTE: __launch_bounds__(256) ONLY — the round-8 (256,4) min-waves cap forced
// VGPR=64 and spilled the flash loop (WRITE_SIZE 159 MB of scratch). Never cap
// this kernel below ~128 VGPR.
__global__ __launch_bounds__(256) void fused_kernel(
    const float* __restrict__ x_non, const float* __restrict__ x_seq,
    const int* __restrict__ mask,
    const float* __restrict__ Wq, const float* __restrict__ bq,
    const float* __restrict__ Wk, const float* __restrict__ bk,
    const float* __restrict__ Wv, const float* __restrict__ bv,
    float* __restrict__ out)
{
    const int tid = threadIdx.x;
    const int b   = blockIdx.x;
    const float* Xb = x_seq + (size_t)b * (SS * DD);

    const int hp    = tid >> 6;        // wave id; heads 2hp, 2hp+1 in flash
    const int rhalf = (tid >> 5) & 1;  // chunk row half
    const int k16   = tid & 31;        // 16-col group: cols {k16*2 + 64p}
    const int wid   = tid >> 6;
    const int lane  = tid & 63;

    __shared__ __attribute__((aligned(16))) union {
        double T[8][512];              // 32 KB: t, head-major (pre-flash)
        float  Xs[2][8][512];          // 32 KB: double-buffered X chunks (flash)
        float  U[8][512];              // 16 KB: normalized u' (Z phase)
    } sh;
    __shared__ __attribute__((aligned(16))) union {
        double qd[512];                // 4 KB: q[b] (pre-flash)
        int    mk[1024];               // 4 KB: mask[b] (flash)
    } sh2;
    __shared__ double qbks[8];
    __shared__ __attribute__((aligned(16))) float xns[512];

    float* XsF = &sh.Xs[0][0][0];

    // ---- Phase Q: q[b] (f64), replaces qproj kernel + qws roundtrip ----
    xns[tid]       = x_non[(size_t)b * DD + tid];
    xns[tid + 256] = x_non[(size_t)b * DD + tid + 256];
    __syncthreads();

    {
        // lane's x fragment (k = lane*8 .. +7), hoisted to f64 regs once
        double xd[8];
        {
            f4 xa = *(const f4*)&xns[lane * 8];
            f4 xb = *(const f4*)&xns[lane * 8 + 4];
            xd[0] = (double)xa[0]; xd[1] = (double)xa[1];
            xd[2] = (double)xa[2]; xd[3] = (double)xa[3];
            xd[4] = (double)xb[0]; xd[5] = (double)xb[1];
            xd[6] = (double)xb[2]; xd[7] = (double)xb[3];
        }
        // wave w computes outputs o = w*128 .. +127; coalesced Wq row reads
        #pragma unroll 2
        for (int i = 0; i < 128; ++i) {
            const int o = wid * 128 + i;
            const float* wp = Wq + (size_t)o * DD + lane * 8;
            f4 wa = *(const f4*)wp;
            f4 wb = *(const f4*)(wp + 4);
            double a = 0.0;
            a = fma((double)wa[0], xd[0], a);
            a = fma((double)wa[1], xd[1], a);
            a = fma((double)wa[2], xd[2], a);
            a = fma((double)wa[3], xd[3], a);
            a = fma((double)wb[0], xd[4], a);
            a = fma((double)wb[1], xd[5], a);
            a = fma((double)wb[2], xd[6], a);
            a = fma((double)wb[3], xd[7], a);
            #pragma unroll
            for (int off = 1; off < 64; off <<= 1) a += __shfl_xor(a, off);
            if (lane == 0) sh2.qd[o] = a + (double)bq[o];
        }
    }
    __syncthreads();

    // ---- qbk[h] = q_h . bk_h (wave 0, 8 lanes per head) ----
    if (tid < 64) {
        const int h = tid >> 3, part = tid & 7;
        double s = 0.0;
        #pragma unroll
        for (int ii = 0; ii < 8; ++ii) {
            int d = part * 8 + ii;
            s = fma(sh2.qd[h * DHH + d], (double)bk[h * DHH + d], s);
        }
        s += __shfl_xor(s, 1);
        s += __shfl_xor(s, 2);
        s += __shfl_xor(s, 4);
        if (part == 0) qbks[h] = s;
    }

    // ---- t: lanes = k (coalesced f4 Wk loads); d split across thread halves ----
    {
        const int kg = tid & 127, dh = tid >> 7;
        const int k4 = kg * 4;
        for (int hg = 0; hg < 2; ++hg) {
            double tacc[4][4];
            #pragma unroll
            for (int h4 = 0; h4 < 4; ++h4) {
                const int h = hg * 4 + h4;
                const float* wp = Wk + ((size_t)(h * DHH + dh * 32)) * DD + k4;
                double t0 = 0, t1 = 0, t2 = 0, t3 = 0;
                for (int d = 0; d < 32; ++d) {
                    f4 wv = *(const f4*)(wp + (size_t)d * DD);
                    double qv = sh2.qd[h * DHH + dh * 32 + d];
                    t0 = fma((double)wv[0], qv, t0);
                    t1 = fma((double)wv[1], qv, t1);
                    t2 = fma((double)wv[2], qv, t2);
                    t3 = fma((double)wv[3], qv, t3);
                }
                tacc[h4][0] = t0; tacc[h4][1] = t1; tacc[h4][2] = t2; tacc[h4][3] = t3;
            }
            if (dh == 1) {
                #pragma unroll
                for (int h4 = 0; h4 < 4; ++h4)
                    #pragma unroll
                    for (int e = 0; e < 4; ++e)
                        sh.T[hg * 4 + h4][k4 + e] = tacc[h4][e];
            }
            __syncthreads();
            if (dh == 0) {
                #pragma unroll
                for (int h4 = 0; h4 < 4; ++h4)
                    #pragma unroll
                    for (int e = 0; e < 4; ++e)
                        sh.T[hg * 4 + h4][k4 + e] += tacc[h4][e];
            }
            __syncthreads();
        }
    }

    // ---- t fragments to registers ----
    d2 treg[2][8];
    #pragma unroll
    for (int hh = 0; hh < 2; ++hh)
        #pragma unroll
        for (int p = 0; p < 8; ++p)
            treg[hh][p] = *(const d2*)&sh.T[hp * 2 + hh][k16 * 2 + 64 * p];
    float qbkf[2] = { (float)qbks[hp * 2], (float)qbks[hp * 2 + 1] };
    __syncthreads();                       // T fully read; Xs may be written

    // ---- stage mask[b] (reuses qd space) + first X chunk ----
    #pragma unroll
    for (int p = 0; p < 4; ++p)
        sh2.mk[tid + 256 * p] = mask[(size_t)b * (NHH * SS) + tid + 256 * p];
    stage_chunk(Xb, 0, 0, tid, XsF);
    asm volatile("s_waitcnt vmcnt(0)");
    __syncthreads();

    // ---- flash loop over 16 chunks of 8 rows (verified round-1 structure) ----
    float u[2][16];
    #pragma unroll
    for (int hh = 0; hh < 2; ++hh)
        #pragma unroll
        for (int j = 0; j < 16; ++j) u[hh][j] = 0.f;
    float m_run[2] = { -1e30f, -1e30f };
    float l_run[2] = { 0.f, 0.f };

    for (int c = 0; c < 16; ++c) {
        const int buf = c & 1;
        if (c < 15) stage_chunk(Xb, c + 1, buf ^ 1, tid, XsF);

        const float* Xc = XsF + buf * 4096 + (rhalf * 4) * DD + k16 * 2;

        double acc[2][4];
        #pragma unroll
        for (int hh = 0; hh < 2; ++hh)
            #pragma unroll
            for (int r = 0; r < 4; ++r) acc[hh][r] = 0.0;

        #pragma unroll
        for (int r = 0; r < 4; ++r) {
            #pragma unroll
            for (int p = 0; p < 8; ++p) {
                f2 xv = *(const f2*)&Xc[r * DD + p * 64];
                double x0 = (double)xv[0], x1 = (double)xv[1];
                #pragma unroll
                for (int hh = 0; hh < 2; ++hh) {
                    acc[hh][r] = fma(x0, treg[hh][p][0], acc[hh][r]);
                    acc[hh][r] = fma(x1, treg[hh][p][1], acc[hh][r]);
                }
            }
        }

        float Lown[2][4];
        #pragma unroll
        for (int hh = 0; hh < 2; ++hh)
            #pragma unroll
            for (int r = 0; r < 4; ++r) {
                float s = (float)acc[hh][r];
                s += __shfl_xor(s, 1);
                s += __shfl_xor(s, 2);
                s += __shfl_xor(s, 4);
                s += __shfl_xor(s, 8);
                s += __shfl_xor(s, 16);
                s = floorf((s + qbkf[hh]) * 0.125f);
                const int row = c * 8 + rhalf * 4 + r;
                if (sh2.mk[(hp * 2 + hh) * SS + row] == 0) s = -1e9f;
                Lown[hh][r] = s;
            }

        float pw[2][4];
        #pragma unroll
        for (int hh = 0; hh < 2; ++hh) {
            float Loth[4];
            #pragma unroll
            for (int r = 0; r < 4; ++r) Loth[r] = __shfl_xor(Lown[hh][r], 32);
            float cmax = fmaxf(
                fmaxf(fmaxf(Lown[hh][0], Lown[hh][1]), fmaxf(Lown[hh][2], Lown[hh][3])),
                fmaxf(fmaxf(Loth[0], Loth[1]), fmaxf(Loth[2], Loth[3])));
            float mnew = fmaxf(m_run[hh], cmax);
            if (mnew != m_run[hh]) {
                float fs = __expf(m_run[hh] - mnew);
                #pragma unroll
                for (int j = 0; j < 16; ++j) u[hh][j] *= fs;
                l_run[hh] *= fs;
                m_run[hh] = mnew;
            }
            float ps = 0.f;
            #pragma unroll
            for (int r = 0; r < 4; ++r) { pw[hh][r] = __expf(Lown[hh][r] - mnew); ps += pw[hh][r]; }
            #pragma unroll
            for (int r = 0; r < 4; ++r) ps += __expf(Loth[r] - mnew);
            l_run[hh] += ps;
        }

        #pragma unroll
        for (int r = 0; r < 4; ++r) {
            #pragma unroll
            for (int p = 0; p < 8; ++p) {
                f2 xv = *(const f2*)&Xc[r * DD + p * 64];
                #pragma unroll
                for (int hh = 0; hh < 2; ++hh) {
                    u[hh][p * 2]     = fmaf(pw[hh][r], xv[0], u[hh][p * 2]);
                    u[hh][p * 2 + 1] = fmaf(pw[hh][r], xv[1], u[hh][p * 2 + 1]);
                }
            }
        }

        asm volatile("s_waitcnt vmcnt(0)");
        __syncthreads();
    }

    // ---- merge row-halves; write normalized u' to LDS (replaces uws) ----
    #pragma unroll
    for (int hh = 0; hh < 2; ++hh)
        #pragma unroll
        for (int j = 0; j < 16; ++j) u[hh][j] += __shfl_xor(u[hh][j], 32);

    {
        const int h = hp * 2 + rhalf;       // lane owns one head after merge
        const float inv = 1.0f / (rhalf ? l_run[1] : l_run[0]);
        #pragma unroll
        for (int p = 0; p < 8; ++p) {
            f2 v;
            v[0] = (rhalf ? u[1][p * 2]     : u[0][p * 2])     * inv;
            v[1] = (rhalf ? u[1][p * 2 + 1] : u[0][p * 2 + 1]) * inv;
            *(f2*)&sh.U[h][k16 * 2 + p * 64] = v;
        }
    }
    __syncthreads();

    // ---- Phase Z: z[b, h*64+j] = u'[h] . Wv[o] + bv[o] (replaces zout) ----
    #pragma unroll
    for (int hh2 = 0; hh2 < 2; ++hh2) {
        const int h = wid * 2 + hh2;       // wave covers o = wid*128 .. +127
        f4 ua = *(const f4*)&sh.U[h][lane * 8];
        f4 ub = *(const f4*)&sh.U[h][lane * 8 + 4];
        #pragma unroll 2
        for (int j = 0; j < 64; ++j) {
            const int o = h * 64 + j;
            const float* wp = Wv + (size_t)o * DD + lane * 8;
            f4 wa = *(const f4*)wp;
            f4 wb = *(const f4*)(wp + 4);
            float a = 0.f;
            a = fmaf(wa[0], ua[0], a);
            a = fmaf(wa[1], ua[1], a);
            a = fmaf(wa[2], ua[2], a);
            a = fmaf(wa[3], ua[3], a);
            a = fmaf(wb[0], ub[0], a);
            a = fmaf(wb[1], ub[1], a);
            a = fmaf(wb[2], ub[2], a);
            a = fmaf(wb[3], ub[3], a);
            #pragma unroll
            for (int off = 1; off < 64; off <<= 1) a += __shfl_xor(a, off);
            if (lane == 0) out[(size_t)b * DD + o] = a + bv[o];
        }
    }
}

extern "C" void kernel_launch(void* const* d_in, const int* in_sizes, int n_in,
                              void* d_out, int out_size, void* d_ws, size_t ws_size,
                              hipStream_t stream) {
    const float* x_non = (const float*)d_in[0];
    const float* x_seq = (const float*)d_in[1];
    const int*   mask  = (const int*)d_in[2];
    const float* Wq    = (const float*)d_in[3];
    const float* bq    = (const float*)d_in[4];
    const float* Wk    = (const float*)d_in[5];
    const float* bk    = (const float*)d_in[6];
    const float* Wv    = (const float*)d_in[7];
    const float* bv    = (const float*)d_in[8];
    float*       out   = (float*)d_out;

    fused_kernel<<<1024, 256, 0, stream>>>(x_non, x_seq, mask,
                                           Wq, bq, Wk, bk, Wv, bv, out);
}

// Round 11
// 479.611 us; speedup vs baseline: 1.5610x; 1.5594x over previous
//
#include <hip/hip_runtime.h>

#define SS  128
#define DD  512
#define NHH 8
#define DHH 64

typedef float  f4 __attribute__((ext_vector_type(4)));
typedef float  f2 __attribute__((ext_vector_type(2)));
typedef double d2 __attribute__((ext_vector_type(2)));

typedef const void __attribute__((address_space(1)))* gas_t;
typedef void __attribute__((address_space(3)))* las_t;

// ================= K1: q[b,o] = x_non[b] . Wq[o,:] + bq[o]  (f64 acc) =========
// v2: 512 threads, in-block K-split (kh=0: K 0..255, kh=1: K 256..511).
__global__ __launch_bounds__(512) void qproj_kernel(
    const float* __restrict__ x_non, const float* __restrict__ Wq,
    const float* __restrict__ bq, double* __restrict__ qws)
{
    const int tid = threadIdx.x;
    const int bt  = blockIdx.x & 31;
    const int ot  = blockIdx.x >> 5;
    const int kh  = tid >> 8;            // K-half (wave-uniform)
    const int t8  = tid & 255;
    const int r   = t8 >> 4, c = t8 & 15;

    __shared__ __attribute__((aligned(16))) float Xs0[32][68];
    __shared__ __attribute__((aligned(16))) float Xs1[32][68];
    __shared__ __attribute__((aligned(16))) float Ws0[64][68];
    __shared__ __attribute__((aligned(16))) float Ws1[64][68];

    double acc[2][4];
    #pragma unroll
    for (int i = 0; i < 2; ++i)
        #pragma unroll
        for (int j = 0; j < 4; ++j) acc[i][j] = 0.0;

    for (int kc = 0; kc < 4; ++kc) {
        __syncthreads();
        #pragma unroll
        for (int p = 0; p < 2; ++p) {
            int g  = tid + 512 * p;
            int rr = g >> 5, w = g & 31, hf = w >> 4, cc = (w & 15) * 4;
            f4 v = *(const f4*)(x_non + (size_t)(bt * 32 + rr) * DD + hf * 256 + kc * 64 + cc);
            if (hf) *(f4*)&Xs1[rr][cc] = v; else *(f4*)&Xs0[rr][cc] = v;
        }
        #pragma unroll
        for (int p = 0; p < 4; ++p) {
            int g  = tid + 512 * p;
            int rr = g >> 5, w = g & 31, hf = w >> 4, cc = (w & 15) * 4;
            f4 v = *(const f4*)(Wq + (size_t)(ot * 64 + rr) * DD + hf * 256 + kc * 64 + cc);
            if (hf) *(f4*)&Ws1[rr][cc] = v; else *(f4*)&Ws0[rr][cc] = v;
        }
        __syncthreads();
        const float (*Xh)[68] = kh ? Xs1 : Xs0;
        const float (*Wh)[68] = kh ? Ws1 : Ws0;
        #pragma unroll 4
        for (int kk = 0; kk < 64; ++kk) {
            double a0 = (double)Xh[r][kk];
            double a1 = (double)Xh[r + 16][kk];
            #pragma unroll
            for (int j = 0; j < 4; ++j) {
                double bb = (double)Wh[c + 16 * j][kk];
                acc[0][j] = fma(a0, bb, acc[0][j]);
                acc[1][j] = fma(a1, bb, acc[1][j]);
            }
        }
    }
    __syncthreads();
    double* S = (double*)&Ws0[0][0];
    if (kh == 1) {
        #pragma unroll
        for (int i = 0; i < 2; ++i)
            #pragma unroll
            for (int j = 0; j < 4; ++j) S[t8 * 8 + i * 4 + j] = acc[i][j];
    }
    __syncthreads();
    if (kh == 0) {
        #pragma unroll
        for (int i = 0; i < 2; ++i)
            #pragma unroll
            for (int j = 0; j < 4; ++j) {
                int o = ot * 64 + c + 16 * j;
                qws[(size_t)(bt * 32 + r + 16 * i) * DD + o] =
                    acc[i][j] + S[t8 * 8 + i * 4 + j] + (double)bq[o];
            }
    }
}

// ---- async stage: one 8-row (16 KB) chunk of X into LDS, linear layout -------
__device__ __forceinline__ void stage_chunk(const float* __restrict__ Xb,
                                            int c, int buf, int tid, float* XsF)
{
    const int wid  = tid >> 6;
    const int lane = tid & 63;
    const float* gsrc = Xb + (size_t)c * (8 * DD);
    #pragma unroll
    for (int p = 0; p < 4; ++p) {
        const int gbase = p * 256 + wid * 64;             // 16B-granule index base
        const float* gp = gsrc + (size_t)(gbase + lane) * 4;
        float* lp = XsF + (size_t)buf * 4096 + (size_t)gbase * 4; // wave-uniform
        __builtin_amdgcn_global_load_lds((gas_t)gp, (las_t)lp, 16, 0, 0);
    }
}

// ================= K2: per-b attention core (flash single-pass) ===============
// (verified round-1 kernel; 176 µs, zero spill, VGPR 92)
__global__ __launch_bounds__(256) void core_kernel(
    const double* __restrict__ qws, const float* __restrict__ x_seq,
    const int* __restrict__ mask, const float* __restrict__ Wk,
    const float* __restrict__ bk, float* __restrict__ uws)
{
    const int tid = threadIdx.x;
    const int b   = blockIdx.x;
    const float* Xb = x_seq + (size_t)b * (SS * DD);

    const int hp    = tid >> 6;        // 0..3  (wave id; heads 2hp, 2hp+1)
    const int rhalf = (tid >> 5) & 1;  // chunk row half (rows rhalf*4 .. +4)
    const int k16   = tid & 31;        // 16-col group: cols {k16*2 + 64p}

    __shared__ __attribute__((aligned(16))) union {
        double T[8][512];              // 32 KB: t, head-major (pre-flash only)
        float  Xs[2][8][512];          // 32 KB: double-buffered X chunks
    } sh;
    __shared__ __attribute__((aligned(16))) union {
        double qd[512];                // 4 KB: q[b] (pre-flash only)
        int    mk[1024];               // 4 KB: mask[b] (flash)
    } sh2;
    __shared__ double qbks[8];

    float* XsF = &sh.Xs[0][0][0];

    sh2.qd[tid]       = qws[(size_t)b * DD + tid];
    sh2.qd[tid + 256] = qws[(size_t)b * DD + tid + 256];
    __syncthreads();

    if (tid < 64) {
        const int h = tid >> 3, part = tid & 7;
        double s = 0.0;
        #pragma unroll
        for (int ii = 0; ii < 8; ++ii) {
            int d = part * 8 + ii;
            s = fma(sh2.qd[h * DHH + d], (double)bk[h * DHH + d], s);
        }
        s += __shfl_xor(s, 1);
        s += __shfl_xor(s, 2);
        s += __shfl_xor(s, 4);
        if (part == 0) qbks[h] = s;
    }

    {
        const int kg = tid & 127, dh = tid >> 7;
        const int k4 = kg * 4;
        for (int hg = 0; hg < 2; ++hg) {
            double tacc[4][4];
            #pragma unroll
            for (int h4 = 0; h4 < 4; ++h4) {
                const int h = hg * 4 + h4;
                const float* wp = Wk + ((size_t)(h * DHH + dh * 32)) * DD + k4;
                double t0 = 0, t1 = 0, t2 = 0, t3 = 0;
                for (int d = 0; d < 32; ++d) {
                    f4 wv = *(const f4*)(wp + (size_t)d * DD);
                    double qv = sh2.qd[h * DHH + dh * 32 + d];
                    t0 = fma((double)wv[0], qv, t0);
                    t1 = fma((double)wv[1], qv, t1);
                    t2 = fma((double)wv[2], qv, t2);
                    t3 = fma((double)wv[3], qv, t3);
                }
                tacc[h4][0] = t0; tacc[h4][1] = t1; tacc[h4][2] = t2; tacc[h4][3] = t3;
            }
            if (dh == 1) {
                #pragma unroll
                for (int h4 = 0; h4 < 4; ++h4)
                    #pragma unroll
                    for (int e = 0; e < 4; ++e)
                        sh.T[hg * 4 + h4][k4 + e] = tacc[h4][e];
            }
            __syncthreads();
            if (dh == 0) {
                #pragma unroll
                for (int h4 = 0; h4 < 4; ++h4)
                    #pragma unroll
                    for (int e = 0; e < 4; ++e)
                        sh.T[hg * 4 + h4][k4 + e] += tacc[h4][e];
            }
            __syncthreads();
        }
    }

    d2 treg[2][8];
    #pragma unroll
    for (int hh = 0; hh < 2; ++hh)
        #pragma unroll
        for (int p = 0; p < 8; ++p)
            treg[hh][p] = *(const d2*)&sh.T[hp * 2 + hh][k16 * 2 + 64 * p];
    float qbkf[2] = { (float)qbks[hp * 2], (float)qbks[hp * 2 + 1] };
    __syncthreads();

    #pragma unroll
    for (int p = 0; p < 4; ++p)
        sh2.mk[tid + 256 * p] = mask[(size_t)b * (NHH * SS) + tid + 256 * p];
    stage_chunk(Xb, 0, 0, tid, XsF);
    asm volatile("s_waitcnt vmcnt(0)");
    __syncthreads();

    float u[2][16];
    #pragma unroll
    for (int hh = 0; hh < 2; ++hh)
        #pragma unroll
        for (int j = 0; j < 16; ++j) u[hh][j] = 0.f;
    float m_run[2] = { -1e30f, -1e30f };
    float l_run[2] = { 0.f, 0.f };

    for (int c = 0; c < 16; ++c) {
        const int buf = c & 1;
        if (c < 15) stage_chunk(Xb, c + 1, buf ^ 1, tid, XsF);

        const float* Xc = XsF + buf * 4096 + (rhalf * 4) * DD + k16 * 2;

        double acc[2][4];
        #pragma unroll
        for (int hh = 0; hh < 2; ++hh)
            #pragma unroll
            for (int r = 0; r < 4; ++r) acc[hh][r] = 0.0;

        #pragma unroll
        for (int r = 0; r < 4; ++r) {
            #pragma unroll
            for (int p = 0; p < 8; ++p) {
                f2 xv = *(const f2*)&Xc[r * DD + p * 64];
                double x0 = (double)xv[0], x1 = (double)xv[1];
                #pragma unroll
                for (int hh = 0; hh < 2; ++hh) {
                    acc[hh][r] = fma(x0, treg[hh][p][0], acc[hh][r]);
                    acc[hh][r] = fma(x1, treg[hh][p][1], acc[hh][r]);
                }
            }
        }

        float Lown[2][4];
        #pragma unroll
        for (int hh = 0; hh < 2; ++hh)
            #pragma unroll
            for (int r = 0; r < 4; ++r) {
                float s = (float)acc[hh][r];
                s += __shfl_xor(s, 1);
                s += __shfl_xor(s, 2);
                s += __shfl_xor(s, 4);
                s += __shfl_xor(s, 8);
                s += __shfl_xor(s, 16);
                s = floorf((s + qbkf[hh]) * 0.125f);
                const int row = c * 8 + rhalf * 4 + r;
                if (sh2.mk[(hp * 2 + hh) * SS + row] == 0) s = -1e9f;
                Lown[hh][r] = s;
            }

        float pw[2][4];
        #pragma unroll
        for (int hh = 0; hh < 2; ++hh) {
            float Loth[4];
            #pragma unroll
            for (int r = 0; r < 4; ++r) Loth[r] = __shfl_xor(Lown[hh][r], 32);
            float cmax = fmaxf(
                fmaxf(fmaxf(Lown[hh][0], Lown[hh][1]), fmaxf(Lown[hh][2], Lown[hh][3])),
                fmaxf(fmaxf(Loth[0], Loth[1]), fmaxf(Loth[2], Loth[3])));
            float mnew = fmaxf(m_run[hh], cmax);
            if (mnew != m_run[hh]) {
                float fs = __expf(m_run[hh] - mnew);
                #pragma unroll
                for (int j = 0; j < 16; ++j) u[hh][j] *= fs;
                l_run[hh] *= fs;
                m_run[hh] = mnew;
            }
            float ps = 0.f;
            #pragma unroll
            for (int r = 0; r < 4; ++r) { pw[hh][r] = __expf(Lown[hh][r] - mnew); ps += pw[hh][r]; }
            #pragma unroll
            for (int r = 0; r < 4; ++r) ps += __expf(Loth[r] - mnew);
            l_run[hh] += ps;
        }

        #pragma unroll
        for (int r = 0; r < 4; ++r) {
            #pragma unroll
            for (int p = 0; p < 8; ++p) {
                f2 xv = *(const f2*)&Xc[r * DD + p * 64];
                #pragma unroll
                for (int hh = 0; hh < 2; ++hh) {
                    u[hh][p * 2]     = fmaf(pw[hh][r], xv[0], u[hh][p * 2]);
                    u[hh][p * 2 + 1] = fmaf(pw[hh][r], xv[1], u[hh][p * 2 + 1]);
                }
            }
        }

        asm volatile("s_waitcnt vmcnt(0)");
        __syncthreads();
    }

    #pragma unroll
    for (int hh = 0; hh < 2; ++hh)
        #pragma unroll
        for (int j = 0; j < 16; ++j) u[hh][j] += __shfl_xor(u[hh][j], 32);

    {
        const int h = hp * 2 + rhalf;
        const float inv = 1.0f / (rhalf ? l_run[1] : l_run[0]);
        float* dst = uws + ((size_t)b * NHH + h) * DD + k16 * 2;
        #pragma unroll
        for (int p = 0; p < 8; ++p) {
            f2 v;
            v[0] = (rhalf ? u[1][p * 2]     : u[0][p * 2])     * inv;
            v[1] = (rhalf ? u[1][p * 2 + 1] : u[0][p * 2 + 1]) * inv;
            *(f2*)&dst[p * 64] = v;
        }
    }
}

// ================= K3: z[b, h*64+j] = u'[b,h,:] . Wv[o,:] + bv[o]  (f32) ======
// v2: 512 threads, in-block K-split, same scheme as qproj.
__global__ __launch_bounds__(512) void zout_kernel(
    const float* __restrict__ uws, const float* __restrict__ Wv,
    const float* __restrict__ bv, float* __restrict__ out)
{
    const int tid = threadIdx.x;
    const int bt  = blockIdx.x & 31;
    const int ot  = blockIdx.x >> 5;          // == head h
    const int kh  = tid >> 8;
    const int t8  = tid & 255;
    const int r   = t8 >> 4, c = t8 & 15;

    __shared__ __attribute__((aligned(16))) float Us0[32][68];
    __shared__ __attribute__((aligned(16))) float Us1[32][68];
    __shared__ __attribute__((aligned(16))) float Ws0[64][68];
    __shared__ __attribute__((aligned(16))) float Ws1[64][68];

    float acc[2][4];
    #pragma unroll
    for (int i = 0; i < 2; ++i)
        #pragma unroll
        for (int j = 0; j < 4; ++j) acc[i][j] = 0.f;

    for (int kc = 0; kc < 4; ++kc) {
        __syncthreads();
        #pragma unroll
        for (int p = 0; p < 2; ++p) {
            int g  = tid + 512 * p;
            int rr = g >> 5, w = g & 31, hf = w >> 4, cc = (w & 15) * 4;
            f4 v = *(const f4*)(uws + ((size_t)(bt * 32 + rr) * NHH + ot) * DD
                                + hf * 256 + kc * 64 + cc);
            if (hf) *(f4*)&Us1[rr][cc] = v; else *(f4*)&Us0[rr][cc] = v;
        }
        #pragma unroll
        for (int p = 0; p < 4; ++p) {
            int g  = tid + 512 * p;
            int rr = g >> 5, w = g & 31, hf = w >> 4, cc = (w & 15) * 4;
            f4 v = *(const f4*)(Wv + (size_t)(ot * 64 + rr) * DD + hf * 256 + kc * 64 + cc);
            if (hf) *(f4*)&Ws1[rr][cc] = v; else *(f4*)&Ws0[rr][cc] = v;
        }
        __syncthreads();
        const float (*Uh)[68] = kh ? Us1 : Us0;
        const float (*Wh)[68] = kh ? Ws1 : Ws0;
        #pragma unroll 4
        for (int kk = 0; kk < 64; ++kk) {
            float a0 = Uh[r][kk];
            float a1 = Uh[r + 16][kk];
            #pragma unroll
            for (int j = 0; j < 4; ++j) {
                float bb = Wh[c + 16 * j][kk];
                acc[0][j] = fmaf(a0, bb, acc[0][j]);
                acc[1][j] = fmaf(a1, bb, acc[1][j]);
            }
        }
    }
    __syncthreads();
    float* S = (float*)&Ws0[0][0];
    if (kh == 1) {
        #pragma unroll
        for (int i = 0; i < 2; ++i)
            #pragma unroll
            for (int j = 0; j < 4; ++j) S[t8 * 8 + i * 4 + j] = acc[i][j];
    }
    __syncthreads();
    if (kh == 0) {
        #pragma unroll
        for (int i = 0; i < 2; ++i)
            #pragma unroll
            for (int j = 0; j < 4; ++j) {
                int o = ot * 64 + c + 16 * j;
                out[(size_t)(bt * 32 + r + 16 * i) * DD + o] =
                    acc[i][j] + S[t8 * 8 + i * 4 + j] + bv[o];
            }
    }
}

extern "C" void kernel_launch(void* const* d_in, const int* in_sizes, int n_in,
                              void* d_out, int out_size, void* d_ws, size_t ws_size,
                              hipStream_t stream) {
    const float* x_non = (const float*)d_in[0];
    const float* x_seq = (const float*)d_in[1];
    const int*   mask  = (const int*)d_in[2];
    const float* Wq    = (const float*)d_in[3];
    const float* bq    = (const float*)d_in[4];
    const float* Wk    = (const float*)d_in[5];
    const float* bk    = (const float*)d_in[6];
    const float* Wv    = (const float*)d_in[7];
    const float* bv    = (const float*)d_in[8];
    float*       out   = (float*)d_out;

    double* qws = (double*)d_ws;                                     // 4 MB
    float*  uws = (float*)((char*)d_ws + (size_t)1024 * DD * 8);     // 16 MB

    qproj_kernel<<<256, 512, 0, stream>>>(x_non, Wq, bq, qws);
    core_kernel<<<1024, 256, 0, stream>>>(qws, x_seq, mask, Wk, bk, uws);
    zout_kernel<<<256, 512, 0, stream>>>(uws, Wv, bv, out);
}